// Round 3
// baseline (4939.227 us; speedup 1.0000x reference)
//
#include <hip/hip_runtime.h>
#include <hip/hip_bf16.h>

#define HH 500
#define G4 2000
#define NSEQ 2304
#define NGOALS 256
#define NHYPS 2048
#define LSEQ 128
#define NVOCAB 1000
#define NEG_SLOPE 0.01f

typedef __attribute__((ext_vector_type(4)))  float f32x4;
typedef __attribute__((ext_vector_type(16))) float f32x16;
typedef __attribute__((ext_vector_type(8)))  short short8;

__device__ __forceinline__ float sigm(float x) { return 1.0f / (1.0f + expf(-x)); }

__device__ __forceinline__ void gload_lds16(const void* g, void* l) {
    __builtin_amdgcn_global_load_lds(
        (const __attribute__((address_space(1))) unsigned int*)g,
        (__attribute__((address_space(3))) unsigned int*)l, 16, 0, 0);
}

// ---------- split conversions ----------
__global__ void split_emb(const float* __restrict__ emb,
                          __hip_bfloat16* __restrict__ Eh, __hip_bfloat16* __restrict__ El)
{
    int idx = blockIdx.x * 256 + threadIdx.x;          // 1024*512
    if (idx >= 1024 * 512) return;
    int k = idx & 511, r = idx >> 9;
    float v = (r < NVOCAB && k < HH) ? emb[r * HH + k] : 0.0f;
    __hip_bfloat16 h = __float2bfloat16(v);
    Eh[idx] = h;
    El[idx] = __float2bfloat16(v - __bfloat162float(h));
}

__global__ void split_wih(const float* __restrict__ Wih,
                          __hip_bfloat16* __restrict__ Wh, __hip_bfloat16* __restrict__ Wl)
{
    int idx = blockIdx.x * 256 + threadIdx.x;          // 2000*512
    if (idx >= 2000 * 512) return;
    int k = idx & 511, r = idx >> 9;
    float v = (k < HH) ? Wih[r * HH + k] : 0.0f;
    __hip_bfloat16 h = __float2bfloat16(v);
    Wh[idx] = h;
    Wl[idx] = __float2bfloat16(v - __bfloat162float(h));
}

// Whh fp32 [2000][500] -> bf16 Wb[4][512][512] (gate, u, k), zero-padded
__global__ void conv_whh(const float* __restrict__ Whh, __hip_bfloat16* __restrict__ Wb)
{
    int idx = blockIdx.x * 256 + threadIdx.x;
    if (idx >= 4 * 512 * 512) return;
    int k = idx & 511, u = (idx >> 9) & 511, g = idx >> 18;
    float v = (u < HH && k < HH) ? Whh[(g * HH + u) * HH + k] : 0.0f;
    Wb[idx] = __float2bfloat16(v);
}

// ---------- T table: T4[tok][4][512] = emb @ Wih^T + bih + bhh, split-bf16 ----------
__global__ __launch_bounds__(256) void tgemm_split(
    const __hip_bfloat16* __restrict__ Eh, const __hip_bfloat16* __restrict__ El,
    const __hip_bfloat16* __restrict__ Wh, const __hip_bfloat16* __restrict__ Wl,
    const float* __restrict__ bih, const float* __restrict__ bhh,
    float* __restrict__ T4)
{
    __shared__ char lds[40960];   // dbuf x {Ah 8K, Al 8K, Bh 2K, Bl 2K}
    int tid = threadIdx.x, w = tid >> 6, lane = tid & 63;
    int j0 = blockIdx.x * 16;     // Wih-row tile (output col)
    int m0 = blockIdx.y * 64;     // emb-row tile
    int lrow = lane >> 3, cblk = (lane & 7) ^ lrow, r7 = lane & 7;
    const short* eh = (const short*)Eh; const short* el = (const short*)El;
    const short* wh = (const short*)Wh; const short* wl = (const short*)Wl;
    f32x4 acc = {};
    int arow = w * 16 + (lane & 15);

    auto STAGE = [&](int buf, int k0) {
        char* base = lds + buf * 20480;
        #pragma unroll
        for (int i = 0; i < 2; ++i) {
            int r = (w * 2 + i) * 8 + lrow;
            gload_lds16(eh + (size_t)(m0 + r) * 512 + k0 + cblk * 8, base + (w * 2 + i) * 1024);
            gload_lds16(el + (size_t)(m0 + r) * 512 + k0 + cblk * 8, base + 8192 + (w * 2 + i) * 1024);
        }
        {   // B: Bh 2 issues (w=0,1), Bl 2 issues (w=2,3)
            int half = w & 1;
            int r = half * 8 + lrow;
            const short* src = (w < 2) ? wh : wl;
            int off = (w < 2) ? 16384 : 18432;
            gload_lds16(src + (size_t)(j0 + r) * 512 + 0 + cblk * 8 + k0, base + off + half * 1024);
        }
    };

    STAGE(0, 0);
    __syncthreads();
    int cur = 0;
    for (int ch = 0; ch < 8; ++ch) {
        if (ch < 7) STAGE(cur ^ 1, (ch + 1) * 64);
        char* base = lds + cur * 20480;
        #pragma unroll
        for (int ks = 0; ks < 2; ++ks) {
            int blk = (ks * 4 + (lane >> 4)) ^ r7;
            short8 ah = *(const short8*)(base + arow * 128 + blk * 16);
            short8 al = *(const short8*)(base + 8192 + arow * 128 + blk * 16);
            short8 bh = *(const short8*)(base + 16384 + (lane & 15) * 128 + blk * 16);
            short8 bl = *(const short8*)(base + 18432 + (lane & 15) * 128 + blk * 16);
            acc = __builtin_amdgcn_mfma_f32_16x16x32_bf16(ah, bh, acc, 0, 0, 0);
            acc = __builtin_amdgcn_mfma_f32_16x16x32_bf16(ah, bl, acc, 0, 0, 0);
            acc = __builtin_amdgcn_mfma_f32_16x16x32_bf16(al, bh, acc, 0, 0, 0);
        }
        if (ch < 7) { __syncthreads(); cur ^= 1; }
    }
    int j = j0 + (lane & 15);
    int g = (j >= 1500) ? 3 : (j >= 1000) ? 2 : (j >= 500) ? 1 : 0;
    int u = j - g * 500;
    float bias = bih[j] + bhh[j];
    #pragma unroll
    for (int r = 0; r < 4; ++r) {
        int m = m0 + w * 16 + (lane >> 4) * 4 + r;
        if (m < NVOCAB) T4[(size_t)m * 2048 + g * 512 + u] = acc[r] + bias;
    }
}

// ---------- LSTM step: 1 wave/block, 64n x (4g x 32u), 32x32x16 MFMA ----------
__global__ __launch_bounds__(64) void lstm_step3(
    const float* __restrict__ T4,
    const int* __restrict__ goals, const int* __restrict__ hyps,
    const __hip_bfloat16* __restrict__ Wb,
    const __hip_bfloat16* __restrict__ hin,
    __hip_bfloat16* __restrict__ hout,
    float* __restrict__ c, int tstep)
{
    __shared__ char lds[49152];   // 2 x (A 8192 + B 16384)
    int lane = threadIdx.x;
    int u0 = blockIdx.x * 32, n0 = blockIdx.y * 64;
    int lrow = lane >> 3, l7 = lane & 7;
    const short* hin_s = (const short*)hin;
    const short* wb_s  = (const short*)Wb;
    f32x16 acc[2][4] = {};

    auto STAGE = [&](int buf, int k0) {
        char* As_ = lds + buf * 24576;
        char* Bs_ = As_ + 8192;
        #pragma unroll
        for (int i = 0; i < 8; ++i) {
            int cb = l7 ^ lrow ^ (i & 3);
            gload_lds16(hin_s + (size_t)(n0 + i * 8 + lrow) * 512 + k0 + cb * 8, As_ + i * 1024);
        }
        #pragma unroll
        for (int i = 0; i < 16; ++i) {
            int cb = l7 ^ lrow ^ (i & 3);
            int r = i * 8 + lrow;
            int g = r >> 5, uu = r & 31;
            gload_lds16(wb_s + (size_t)(g * 512 + u0 + uu) * 512 + k0 + cb * 8, Bs_ + i * 1024);
        }
    };

    STAGE(0, 0);
    __syncthreads();
    int cur = 0;
    int l31 = lane & 31;
    int keybase = l7 ^ ((lane >> 3) & 3);
    for (int ch = 0; ch < 8; ++ch) {
        if (ch < 7) STAGE(cur ^ 1, (ch + 1) * 64);
        char* As_ = lds + cur * 24576;
        char* Bs_ = As_ + 8192;
        #pragma unroll
        for (int ks = 0; ks < 4; ++ks) {
            int blk = (ks * 2 + (lane >> 5)) ^ keybase;
            short8 a0 = *(const short8*)(As_ + l31 * 128 + blk * 16);
            short8 a1 = *(const short8*)(As_ + (32 + l31) * 128 + blk * 16);
            #pragma unroll
            for (int g = 0; g < 4; ++g) {
                short8 b = *(const short8*)(Bs_ + (g * 32 + l31) * 128 + blk * 16);
                acc[0][g] = __builtin_amdgcn_mfma_f32_32x32x16_bf16(a0, b, acc[0][g], 0, 0, 0);
                acc[1][g] = __builtin_amdgcn_mfma_f32_32x32x16_bf16(a1, b, acc[1][g], 0, 0, 0);
            }
        }
        if (ch < 7) { __syncthreads(); cur ^= 1; }
    }

    // epilogue: lane u = u0+(lane&31); rows = n0 + r*32 + (reg&3)+8*(reg>>2)+4*(lane>>5)
    int u = u0 + l31;
    if (u < HH) {
        #pragma unroll
        for (int r = 0; r < 2; ++r) {
            #pragma unroll
            for (int reg = 0; reg < 16; ++reg) {
                int n = n0 + r * 32 + (reg & 3) + 8 * (reg >> 2) + 4 * (lane >> 5);
                int tok = (n < NGOALS) ? goals[n * LSEQ + tstep] : hyps[(n - NGOALS) * LSEQ + tstep];
                const float* Tg = T4 + (size_t)tok * 2048;
                float gi = acc[r][0][reg] + Tg[u];
                float gf = acc[r][1][reg] + Tg[512 + u];
                float gg = acc[r][2][reg] + Tg[1024 + u];
                float go = acc[r][3][reg] + Tg[1536 + u];
                float si = sigm(gi), sf = sigm(gf), so = sigm(go);
                float cv = c[(size_t)n * 512 + u];
                cv = sf * cv + si * tanhf(gg);
                c[(size_t)n * 512 + u] = cv;
                hout[(size_t)n * 512 + u] = __float2bfloat16(so * tanhf(cv));
            }
        }
    }
}

// ---------- tail ----------
__global__ void gemm_at_bt(const float* __restrict__ A, const float* __restrict__ B,
                           const float* __restrict__ bias, const float* __restrict__ bias2,
                           float* __restrict__ C, int M, int N, int K, int act)
{
    __shared__ float as[32][17];
    __shared__ float bs[32][17];
    int tid = threadIdx.x;
    int tx = tid & 15, ty = tid >> 4;
    int m0 = blockIdx.y * 32, n0 = blockIdx.x * 32;
    float acc[2][2] = {};
    for (int k0 = 0; k0 < K; k0 += 16) {
        #pragma unroll
        for (int i = 0; i < 2; ++i) {
            int idx = i * 256 + tid;
            int r = idx >> 4, k = idx & 15;
            int gm = m0 + r, gk = k0 + k;
            as[r][k] = (gm < M && gk < K) ? A[gm * K + gk] : 0.0f;
            int gn = n0 + r;
            bs[r][k] = (gn < N && gk < K) ? B[gn * K + gk] : 0.0f;
        }
        __syncthreads();
        #pragma unroll
        for (int kk = 0; kk < 16; ++kk) {
            float a0 = as[ty][kk], a1 = as[ty + 16][kk];
            float b0 = bs[tx][kk], b1 = bs[tx + 16][kk];
            acc[0][0] += a0 * b0; acc[0][1] += a0 * b1;
            acc[1][0] += a1 * b0; acc[1][1] += a1 * b1;
        }
        __syncthreads();
    }
    #pragma unroll
    for (int i = 0; i < 2; ++i) {
        int m = m0 + ty + i * 16;
        if (m >= M) continue;
        #pragma unroll
        for (int j = 0; j < 2; ++j) {
            int n = n0 + tx + j * 16;
            if (n >= N) continue;
            float v = acc[i][j];
            if (bias)  v += bias[n];
            if (bias2) v += bias2[n];
            if (act == 1) v = (v >= 0.0f) ? v : NEG_SLOPE * v;
            C[m * N + n] = v;
        }
    }
}

__global__ void segsum_bf(const __hip_bfloat16* __restrict__ hfin,
                          const int* __restrict__ segid, float* __restrict__ hyp_sum)
{
    int row = blockIdx.y;
    int u = blockIdx.x * 256 + threadIdx.x;
    if (u >= HH) return;
    int b = segid[row];
    atomicAdd(&hyp_sum[b * HH + u],
              __bfloat162float(hfin[(size_t)(NGOALS + row) * 512 + u]));
}

__global__ void concat_bf(const __hip_bfloat16* __restrict__ hfin,
                          const float* __restrict__ hyp_sum, float* __restrict__ xcat)
{
    int r = blockIdx.y;
    int k = blockIdx.x * 256 + threadIdx.x;
    if (k >= 2 * HH) return;
    xcat[r * 2 * HH + k] = (k < HH) ? __bfloat162float(hfin[(size_t)r * 512 + k])
                                    : hyp_sum[r * HH + (k - HH)];
}

__global__ void rownorm(const float* __restrict__ X, float* __restrict__ out)
{
    __shared__ float red[256];
    int r = blockIdx.x;
    int tid = threadIdx.x;
    float v0 = (tid < HH) ? X[r * HH + tid] : 0.0f;
    float v1 = (tid + 256 < HH) ? X[r * HH + tid + 256] : 0.0f;
    red[tid] = v0 * v0 + v1 * v1;
    __syncthreads();
    for (int st = 128; st > 0; st >>= 1) {
        if (tid < st) red[tid] += red[tid + st];
        __syncthreads();
    }
    float nrm = fmaxf(sqrtf(red[0]), 1e-12f);
    if (tid < HH) out[r * HH + tid] = v0 / nrm;
    if (tid + 256 < HH) out[r * HH + tid + 256] = v1 / nrm;
}

extern "C" void kernel_launch(void* const* d_in, const int* in_sizes, int n_in,
                              void* d_out, int out_size, void* d_ws, size_t ws_size,
                              hipStream_t stream)
{
    const int*   goals = (const int*)d_in[0];
    const int*   hyps  = (const int*)d_in[1];
    const int*   segid = (const int*)d_in[2];
    const float* emb   = (const float*)d_in[3];
    const float* Wih   = (const float*)d_in[4];
    const float* Whh   = (const float*)d_in[5];
    const float* bih   = (const float*)d_in[6];
    const float* bhh   = (const float*)d_in[7];
    const float* W1    = (const float*)d_in[8];
    const float* b1    = (const float*)d_in[9];
    const float* W2    = (const float*)d_in[10];
    const float* b2    = (const float*)d_in[11];
    const float* Wf    = (const float*)d_in[12];
    const float* bf    = (const float*)d_in[13];
    float* out = (float*)d_out;

    char* base = (char*)d_ws;
    float*          T4   = (float*)(base + 0);                  // 1000*2048*4 = 8,192,000
    __hip_bfloat16* Wb   = (__hip_bfloat16*)(base + 8192000);   // 2,097,152
    __hip_bfloat16* hb0  = (__hip_bfloat16*)(base + 10289152);  // 2,359,296
    __hip_bfloat16* hb1  = (__hip_bfloat16*)(base + 12648448);  // 2,359,296
    float*          c    = (float*)(base + 15007744);           // 4,718,592
    float*          hsum = (float*)(base + 19726336);           //   512,000
    float*          xcat = (float*)(base + 20238336);           // 1,024,000
    float*          x1   = (float*)(base + 21262336);           //   512,000
    float*          x2   = (float*)(base + 21774336);           //   512,000
    // transient aliases (consumed before hb/c are zeroed)
    __hip_bfloat16* Eh = (__hip_bfloat16*)(base + 10289152);    // in hb0, 1,048,576
    __hip_bfloat16* El = (__hip_bfloat16*)(base + 11337728);    // in hb0, 1,048,576
    __hip_bfloat16* Wh = (__hip_bfloat16*)(base + 12648448);    // in hb1, 2,048,000
    __hip_bfloat16* Wl = (__hip_bfloat16*)(base + 15007744);    // in c,   2,048,000

    split_emb<<<2048, 256, 0, stream>>>(emb, Eh, El);
    split_wih<<<4000, 256, 0, stream>>>(Wih, Wh, Wl);
    conv_whh<<<4096, 256, 0, stream>>>(Whh, Wb);
    tgemm_split<<<dim3(125, 16), 256, 0, stream>>>(Eh, El, Wh, Wl, bih, bhh, T4);

    hipMemsetAsync(hb0,  0, 2359296, stream);
    hipMemsetAsync(hb1,  0, 2359296, stream);
    hipMemsetAsync(c,    0, 4718592, stream);
    hipMemsetAsync(hsum, 0,  512000, stream);

    __hip_bfloat16* hb[2] = { hb0, hb1 };
    for (int t = 0; t < LSEQ; ++t) {
        lstm_step3<<<dim3(16, 36), 64, 0, stream>>>(
            T4, goals, hyps, Wb, hb[t & 1], hb[(t + 1) & 1], c, t);
    }
    __hip_bfloat16* hfin = hb0;

    segsum_bf<<<dim3(2, NHYPS), 256, 0, stream>>>(hfin, segid, hsum);
    concat_bf<<<dim3(4, NGOALS), 256, 0, stream>>>(hfin, hsum, xcat);

    gemm_at_bt<<<dim3(16, 8), 256, 0, stream>>>(xcat, W1, b1, nullptr, x1, NGOALS, HH, 2 * HH, 1);
    gemm_at_bt<<<dim3(16, 8), 256, 0, stream>>>(x1,   W2, b2, nullptr, x2, NGOALS, HH, HH, 1);
    gemm_at_bt<<<dim3(16, 8), 256, 0, stream>>>(x2,   Wf, bf, nullptr, xcat, NGOALS, HH, HH, 0);
    rownorm<<<NGOALS, 256, 0, stream>>>(xcat, out);
}